// Round 6
// baseline (30.322 us; speedup 1.0000x reference)
//
#include <hip/hip_runtime.h>
#include <hip/hip_bf16.h>

#define TCTX 500
#define DFEAT 8192
#define BDW 8                  // d-columns per (single-wave) block
#define TTW 128                // t-values per block
#define LDS_S 136              // floats; 16B-aligned rows (136*4=544B), non-pow2 banks

typedef float v4f __attribute__((ext_vector_type(4)));

__global__ __launch_bounds__(64) void MegaMerge_77283641524594_kernel(
    const float* __restrict__ h,
    const float* __restrict__ c2q,
    const float* __restrict__ q2c,
    float* __restrict__ out)
{
    // Single-wave workgroup: barrier is free, wave schedules independently.
    __shared__ float hs[BDW * LDS_S];   // 4352 B

    const int tid = threadIdx.x;        // 0..63
    const int d0  = blockIdx.x * BDW;
    const int t0  = blockIdx.y * TTW;

    // Store-phase mapping: 64 lanes = 2 row-groups x 32 t4-lanes.
    const int t4   = tid & 31;          // float4 index along t within tile
    const int rowg = tid >> 5;          // 0..1 -> rows rowg*4 .. rowg*4+3
    const int t    = t0 + t4 * 4;
    const bool act = (t < TCTX);        // 500 % 4 == 0 -> full float4 when active

    // ---- Issue c2q/q2c loads FIRST (deepest latency, independent of LDS) ----
    v4f cpre[4], qpre[4];
    if (act) {
        #pragma unroll
        for (int k = 0; k < 4; ++k) {
            const size_t j = (size_t)(d0 + rowg * 4 + k);
            cpre[k] = *reinterpret_cast<const v4f*>(&c2q[j * TCTX + t]);
            qpre[k] = *reinterpret_cast<const v4f*>(&q2c[j * TCTX + t]);
        }
    }

    // ---- Stage h[t, d0:d0+8] transposed into wave-private LDS ----
    // 2 lanes x float4 cover 8 d-floats; 32 t-rows per pass; 4 passes.
    {
        const int dc = (tid & 1) * 4;   // 0 or 4
        const int tr = tid >> 1;        // 0..31
        #pragma unroll
        for (int p = 0; p < 4; ++p) {
            const int tl = p * 32 + tr;
            const int tg = t0 + tl;
            if (tg < TCTX) {
                const v4f v = *reinterpret_cast<const v4f*>(
                    &h[(size_t)tg * DFEAT + d0 + dc]);
                hs[(dc + 0) * LDS_S + tl] = v.x;   // <=2-way bank aliasing (free)
                hs[(dc + 1) * LDS_S + tl] = v.y;
                hs[(dc + 2) * LDS_S + tl] = v.z;
                hs[(dc + 3) * LDS_S + tl] = v.w;
            }
        }
    }
    __syncthreads();   // single-wave group: compiles to waitcnt + trivial barrier

    // ---- Store phase: cached float4 writes, 512B contiguous runs ----
    if (act) {
        const size_t sec = (size_t)DFEAT * TCTX;
        #pragma unroll
        for (int k = 0; k < 4; ++k) {
            const int dl = rowg * 4 + k;
            const size_t j = (size_t)(d0 + dl);
            const v4f hv = *reinterpret_cast<const v4f*>(
                &hs[dl * LDS_S + t4 * 4]);   // 16B-aligned, ~2-way max
            const v4f c = cpre[k];
            const v4f q = qpre[k];
            const v4f hc = hv * c;
            const v4f hq = hv * q;
            const size_t o = j * TCTX + t;
            *reinterpret_cast<v4f*>(&out[o          ]) = hv;  // H^T
            *reinterpret_cast<v4f*>(&out[o + sec    ]) = c;   // c2q copy
            *reinterpret_cast<v4f*>(&out[o + 2 * sec]) = hc;  // H*C
            *reinterpret_cast<v4f*>(&out[o + 3 * sec]) = hq;  // H*Q
        }
    }
}

extern "C" void kernel_launch(void* const* d_in, const int* in_sizes, int n_in,
                              void* d_out, int out_size, void* d_ws, size_t ws_size,
                              hipStream_t stream) {
    const float* h   = (const float*)d_in[0];
    const float* c2q = (const float*)d_in[1];
    const float* q2c = (const float*)d_in[2];
    float* out = (float*)d_out;

    dim3 grid(DFEAT / BDW, (TCTX + TTW - 1) / TTW);  // 1024 x 4 = 4096 blocks
    dim3 block(64);                                   // single-wave workgroups
    MegaMerge_77283641524594_kernel<<<grid, block, 0, stream>>>(h, c2q, q2c, out);
}

// Round 7
// 24.035 us; speedup vs baseline: 1.2616x; 1.2616x over previous
//
#include <hip/hip_runtime.h>
#include <hip/hip_bf16.h>

#define TCTX 500
#define DFEAT 8192
#define BD 128                // d-columns per block -> 512B contiguous h-row reads
#define TT 128                // t-values per block -> 512B write runs
#define LDS_S (TT + 4)        // padded stride (floats), 16B-aligned rows

typedef float v4f __attribute__((ext_vector_type(4)));

__global__ __launch_bounds__(512) void MegaMerge_77283641524594_kernel(
    const float* __restrict__ h,
    const float* __restrict__ c2q,
    const float* __restrict__ q2c,
    float* __restrict__ out)
{
    __shared__ float hs[BD * LDS_S];   // 67584 B

    const int tid = threadIdx.x;
    const int d0  = blockIdx.x * BD;
    const int t0  = blockIdx.y * TT;

    // Store-phase mapping: 512 thr = 16 row-groups x 32 t4-lanes.
    const int t4   = tid & 31;
    const int rowg = tid >> 5;          // 0..15; rows rowg, rowg+16, ..., rowg+112
    const int t    = t0 + t4 * 4;
    const bool act = (t < TCTX);

    // ---- Prefetch c2q/q2c into regs (independent of LDS; issue early) ----
    v4f cpre[8], qpre[8];
    if (act) {
        #pragma unroll
        for (int k = 0; k < 8; ++k) {
            const size_t j = (size_t)(d0 + rowg + 16 * k);
            cpre[k] = *reinterpret_cast<const v4f*>(&c2q[j * TCTX + t]);
            qpre[k] = *reinterpret_cast<const v4f*>(&q2c[j * TCTX + t]);
        }
    }

    // ---- Stage h[t, d0:d0+128] transposed into LDS ----
    // 32 lanes x float4 = 512B contiguous per h-row; 16 rows/pass; 8 passes.
    {
        const int dc = (tid & 31) * 4;  // 0,4,...,124
        const int tr = tid >> 5;        // 0..15
        #pragma unroll
        for (int p = 0; p < 8; ++p) {
            const int tl = p * 16 + tr;
            const int tg = t0 + tl;
            if (tg < TCTX) {
                const v4f v = *reinterpret_cast<const v4f*>(
                    &h[(size_t)tg * DFEAT + d0 + dc]);
                hs[(dc + 0) * LDS_S + tl] = v.x;   // 2-way aliasing max (free)
                hs[(dc + 1) * LDS_S + tl] = v.y;
                hs[(dc + 2) * LDS_S + tl] = v.z;
                hs[(dc + 3) * LDS_S + tl] = v.w;
            }
        }
    }
    __syncthreads();

    // ---- Store phase: cached float4 writes, 512B runs per section ----
    if (act) {
        const size_t sec = (size_t)DFEAT * TCTX;
        #pragma unroll
        for (int k = 0; k < 8; ++k) {
            const int dl = rowg + 16 * k;
            const size_t j = (size_t)(d0 + dl);
            const v4f hv = *reinterpret_cast<const v4f*>(
                &hs[dl * LDS_S + t4 * 4]);
            const v4f c = cpre[k];
            const v4f q = qpre[k];
            const v4f hc = hv * c;
            const v4f hq = hv * q;
            const size_t o = j * TCTX + t;
            *reinterpret_cast<v4f*>(&out[o          ]) = hv;  // H^T
            *reinterpret_cast<v4f*>(&out[o + sec    ]) = c;   // c2q copy
            *reinterpret_cast<v4f*>(&out[o + 2 * sec]) = hc;  // H*C
            *reinterpret_cast<v4f*>(&out[o + 3 * sec]) = hq;  // H*Q
        }
    }
}

extern "C" void kernel_launch(void* const* d_in, const int* in_sizes, int n_in,
                              void* d_out, int out_size, void* d_ws, size_t ws_size,
                              hipStream_t stream) {
    const float* h   = (const float*)d_in[0];
    const float* c2q = (const float*)d_in[1];
    const float* q2c = (const float*)d_in[2];
    float* out = (float*)d_out;

    dim3 grid(DFEAT / BD, (TCTX + TT - 1) / TT);  // 64 x 4 = 256 blocks
    dim3 block(512);
    MegaMerge_77283641524594_kernel<<<grid, block, 0, stream>>>(h, c2q, q2c, out);
}